// Round 7
// baseline (227.143 us; speedup 1.0000x reference)
//
#include <hip/hip_runtime.h>

// ---------------------------------------------------------------------------
// AttentionOT  (Nq=64, M=16, B=8, K=256, C=512)
//   Front (error-critical, feeds exp(20*sim)): bf16x3 split MFMA (Markidis),
//     operands pre-split by a memory-bound prep pass.
//   Back half: plain bf16 MFMA, weights precast.
//   Sinkhorn: rotated dual layouts + DPP; NEW round 7: 2 problems per wave
//     (independent chains hide each other's DS/DPP/rcp latency; kernel wall
//     is each wave's serial 100-iter chain, so ILP-2 within the wave is the
//     only lever) + 3-parallel shfl_xor(16/32/48) = one DS round-trip.
//   7 dispatches: prep -> qkv -> rownorm -> sim -> sinkhorn -> T@V -> proj.
// ---------------------------------------------------------------------------

typedef short   short8  __attribute__((ext_vector_type(8)));
typedef float   floatx4 __attribute__((ext_vector_type(4)));

static __device__ __forceinline__ float fastrcp(float x) {
    return __builtin_amdgcn_rcpf(x);
}
static __device__ __forceinline__ unsigned short f2bf(float f) {
    union { float f; unsigned u; } c; c.f = f;
    unsigned r = c.u + 0x7FFF + ((c.u >> 16) & 1);   // RNE
    return (unsigned short)(r >> 16);
}
static __device__ __forceinline__ float bf2f(unsigned short h) {
    union { unsigned u; float f; } c; c.u = (unsigned)h << 16;
    return c.f;
}

#define RRI(x, C) __builtin_amdgcn_update_dpp(0, (x), (C), 0xf, 0xf, true)
#define RRF(x, C) __int_as_float(RRI(__float_as_int(x), (C)))
#define GATH16(d, s) do { d[0] = (s);                                        \
    d[1]  = RRF((s), 0x121); d[2]  = RRF((s), 0x122);                        \
    d[3]  = RRF((s), 0x123); d[4]  = RRF((s), 0x124);                        \
    d[5]  = RRF((s), 0x125); d[6]  = RRF((s), 0x126);                        \
    d[7]  = RRF((s), 0x127); d[8]  = RRF((s), 0x128);                        \
    d[9]  = RRF((s), 0x129); d[10] = RRF((s), 0x12a);                        \
    d[11] = RRF((s), 0x12b); d[12] = RRF((s), 0x12c);                        \
    d[13] = RRF((s), 0x12d); d[14] = RRF((s), 0x12e);                        \
    d[15] = RRF((s), 0x12f); } while (0)

// ---------------------------------------------------------------------------
// prep: fp32 -> bf16 split (xq,xk,Wq,Wk) / cast (xv,Wv,Wp).
// ---------------------------------------------------------------------------
__global__ __launch_bounds__(256) void prep(
    const float* __restrict__ xq, const float* __restrict__ xk,
    const float* __restrict__ xv, const float* __restrict__ Wq,
    const float* __restrict__ Wk, const float* __restrict__ Wv,
    const float* __restrict__ Wp,
    unsigned short* __restrict__ xqh, unsigned short* __restrict__ xql,
    unsigned short* __restrict__ xkh, unsigned short* __restrict__ xkl,
    unsigned short* __restrict__ xvb,
    unsigned short* __restrict__ wqh, unsigned short* __restrict__ wql,
    unsigned short* __restrict__ wkh, unsigned short* __restrict__ wkl,
    unsigned short* __restrict__ wvb, unsigned short* __restrict__ wpb)
{
    const int b = blockIdx.x;
    const float* src; unsigned short *dh, *dl; long base;
    if (b < 4096)      { src = xq; dh = xqh; dl = xql;     base = (long)b * 256; }
    else if (b < 5120) { src = xk; dh = xkh; dl = xkl;     base = (long)(b - 4096) * 256; }
    else if (b < 6144) { src = xv; dh = xvb; dl = nullptr; base = (long)(b - 5120) * 256; }
    else if (b < 6400) { src = Wq; dh = wqh; dl = wql;     base = (long)(b - 6144) * 256; }
    else if (b < 6656) { src = Wk; dh = wkh; dl = wkl;     base = (long)(b - 6400) * 256; }
    else if (b < 6912) { src = Wv; dh = wvb; dl = nullptr; base = (long)(b - 6656) * 256; }
    else               { src = Wp; dh = wpb; dl = nullptr; base = (long)(b - 6912) * 256; }
    const long i = base + threadIdx.x;
    float4 v = ((const float4*)src)[i];
    ushort4 h;
    h.x = f2bf(v.x); h.y = f2bf(v.y); h.z = f2bf(v.z); h.w = f2bf(v.w);
    ((ushort4*)dh)[i] = h;
    if (dl) {
        ushort4 l;
        l.x = f2bf(v.x - bf2f(h.x)); l.y = f2bf(v.y - bf2f(h.y));
        l.z = f2bf(v.z - bf2f(h.z)); l.w = f2bf(v.w - bf2f(h.w));
        ((ushort4*)dl)[i] = l;
    }
}

// ---------------------------------------------------------------------------
// Fused q/k/v projection on preconverted bf16 operands (round-6, verified).
// ---------------------------------------------------------------------------
__global__ __launch_bounds__(256) void gemm_qkv2(
    const unsigned short* __restrict__ xqh, const unsigned short* __restrict__ xql,
    const unsigned short* __restrict__ xkh, const unsigned short* __restrict__ xkl,
    const unsigned short* __restrict__ xvb,
    const unsigned short* __restrict__ wqh, const unsigned short* __restrict__ wql,
    const unsigned short* __restrict__ wkh, const unsigned short* __restrict__ wkl,
    const unsigned short* __restrict__ wvb,
    unsigned short* __restrict__ qh, unsigned short* __restrict__ ql,
    unsigned short* __restrict__ kh, unsigned short* __restrict__ kl,
    unsigned short* __restrict__ vt)
{
    __shared__ __align__(16) short LB[20480];          // 40 KB
    short (*Ash)[40] = (short(*)[40])(LB);
    short (*Asl)[40] = (short(*)[40])(LB + 5120);
    short (*Bsh)[40] = (short(*)[40])(LB + 10240);
    short (*Bsl)[40] = (short(*)[40])(LB + 15360);

    const int bx = blockIdx.x;
    const unsigned short *Ah, *Al, *Bh, *Bl;
    int seg, arow0;
    if (bx < 64)      { Ah = xqh; Al = xql; Bh = wqh; Bl = wql; arow0 = bx * 128;        seg = 0; }
    else if (bx < 80) { Ah = xkh; Al = xkl; Bh = wkh; Bl = wkl; arow0 = (bx - 64) * 128; seg = 1; }
    else              { Ah = xvb; Al = xvb; Bh = wvb; Bl = wvb; arow0 = (bx - 80) * 128; seg = 2; }
    const bool split = (seg != 2);

    const int tid  = threadIdx.x;
    const int lane = tid & 63, wv = tid >> 6;
    const int wr = (wv >> 1) * 64, wc = (wv & 1) * 64;
    const int j0 = blockIdx.y * 128;

    floatx4 acc[4][4];
#pragma unroll
    for (int i = 0; i < 4; i++)
#pragma unroll
        for (int j = 0; j < 4; j++) acc[i][j] = {0.f, 0.f, 0.f, 0.f};

    const int sr = tid >> 2, sch = (tid & 3) * 8;
    const int fr = lane & 15, fq = (lane >> 4) * 8;

    for (int k0 = 0; k0 < 512; k0 += 32) {
#pragma unroll
        for (int p = 0; p < 2; p++) {
            const int r = sr + p * 64;
            const long ao = (long)(arow0 + r) * 512 + k0 + sch;
            const long bo = (long)(j0 + r) * 512 + k0 + sch;
            *(short8*)&Ash[r][sch] = *(const short8*)(Ah + ao);
            *(short8*)&Bsh[r][sch] = *(const short8*)(Bh + bo);
            if (split) {
                *(short8*)&Asl[r][sch] = *(const short8*)(Al + ao);
                *(short8*)&Bsl[r][sch] = *(const short8*)(Bl + bo);
            }
        }
        __syncthreads();
        short8 ah[4], bh[4];
#pragma unroll
        for (int i = 0; i < 4; i++) ah[i] = *(const short8*)&Ash[wr + i * 16 + fr][fq];
#pragma unroll
        for (int j = 0; j < 4; j++) bh[j] = *(const short8*)&Bsh[wc + j * 16 + fr][fq];
        if (split) {
            short8 al[4], bl[4];
#pragma unroll
            for (int i = 0; i < 4; i++) al[i] = *(const short8*)&Asl[wr + i * 16 + fr][fq];
#pragma unroll
            for (int j = 0; j < 4; j++) bl[j] = *(const short8*)&Bsl[wc + j * 16 + fr][fq];
#pragma unroll
            for (int i = 0; i < 4; i++)
#pragma unroll
                for (int j = 0; j < 4; j++) {
                    acc[i][j] = __builtin_amdgcn_mfma_f32_16x16x32_bf16(ah[i], bh[j], acc[i][j], 0, 0, 0);
                    acc[i][j] = __builtin_amdgcn_mfma_f32_16x16x32_bf16(ah[i], bl[j], acc[i][j], 0, 0, 0);
                    acc[i][j] = __builtin_amdgcn_mfma_f32_16x16x32_bf16(al[i], bh[j], acc[i][j], 0, 0, 0);
                }
        } else {
#pragma unroll
            for (int i = 0; i < 4; i++)
#pragma unroll
                for (int j = 0; j < 4; j++)
                    acc[i][j] = __builtin_amdgcn_mfma_f32_16x16x32_bf16(ah[i], bh[j], acc[i][j], 0, 0, 0);
        }
        __syncthreads();
    }

    const int cr = (lane >> 4) * 4, cc = lane & 15;
    if (seg == 2) {
        short (*S2)[136] = (short(*)[136])LB;
#pragma unroll
        for (int i = 0; i < 4; i++)
#pragma unroll
            for (int j = 0; j < 4; j++)
#pragma unroll
                for (int r = 0; r < 4; r++)
                    S2[wc + j * 16 + cc][wr + i * 16 + cr + r] =
                        (short)f2bf(acc[i][j][r]);
        __syncthreads();
        const int orow = tid >> 1;
        const int os   = (tid & 1) * 64;
        unsigned short* dst = vt + (long)(arow0 >> 8) * 131072
                            + (long)(j0 + orow) * 256 + (arow0 & 255) + os;
#pragma unroll
        for (int c8 = 0; c8 < 8; c8++)
            *(short8*)(dst + c8 * 8) = *(const short8*)&S2[orow][os + c8 * 8];
    } else {
#pragma unroll
        for (int i = 0; i < 4; i++)
#pragma unroll
            for (int j = 0; j < 4; j++) {
                const int gj = j0 + wc + j * 16 + cc;
#pragma unroll
                for (int r = 0; r < 4; r++) {
                    const int gi = arow0 + wr + i * 16 + cr + r;
                    const float v = acc[i][j][r];
                    const unsigned short h = f2bf(v);
                    const unsigned short lo = f2bf(v - bf2f(h));
                    if (seg == 0) {
                        const long orow = (long)((gi & 7) * 1024 + ((gi >> 3) & 15) * 64 + (gi >> 7));
                        qh[orow * 512 + gj] = h;
                        ql[orow * 512 + gj] = lo;
                    } else {
                        kh[(long)gi * 512 + gj] = h;
                        kl[(long)gi * 512 + gj] = lo;
                    }
                }
            }
    }
}

// ---------------------------------------------------------------------------
// sim GEMM, 64x64 tiles (512 blocks), bf16x3, epilogue scale (round-5).
// ---------------------------------------------------------------------------
__global__ __launch_bounds__(256) void gemm_sim64(
    const short* __restrict__ Ah, const short* __restrict__ Al,
    const short* __restrict__ Bh, const short* __restrict__ Bl,
    float* __restrict__ Out, const float* __restrict__ rs)
{
    const int z = blockIdx.z;
    Ah += (long)z * 131072;  Al += (long)z * 131072;
    Bh += (long)z * 524288;  Bl += (long)z * 524288;
    Out += (long)z * 262144;
    const float* rsq = rs + (long)z * 1024;
    const float* rsk = rs + 8192 + (long)z * 256;

    __shared__ __align__(16) short Ash[64][40];
    __shared__ __align__(16) short Asl[64][40];
    __shared__ __align__(16) short Bsh[64][40];
    __shared__ __align__(16) short Bsl[64][40];

    const int tid  = threadIdx.x;
    const int lane = tid & 63, wv = tid >> 6;
    const int wr = (wv >> 1) * 32, wc = (wv & 1) * 32;
    const int i0 = blockIdx.x * 64, j0 = blockIdx.y * 64;

    floatx4 acc[2][2];
#pragma unroll
    for (int i = 0; i < 2; i++)
#pragma unroll
        for (int j = 0; j < 2; j++) acc[i][j] = {0.f, 0.f, 0.f, 0.f};

    const int sr = tid >> 2, sch = (tid & 3) * 8;
    const int fr = lane & 15, fq = (lane >> 4) * 8;

    for (int k0 = 0; k0 < 512; k0 += 32) {
        const long ao = (long)(i0 + sr) * 512 + k0 + sch;
        const long bo = (long)(j0 + sr) * 512 + k0 + sch;
        *(short8*)&Ash[sr][sch] = *(const short8*)(Ah + ao);
        *(short8*)&Asl[sr][sch] = *(const short8*)(Al + ao);
        *(short8*)&Bsh[sr][sch] = *(const short8*)(Bh + bo);
        *(short8*)&Bsl[sr][sch] = *(const short8*)(Bl + bo);
        __syncthreads();
        short8 ah[2], al[2], bh[2], bl[2];
#pragma unroll
        for (int i = 0; i < 2; i++) {
            ah[i] = *(const short8*)&Ash[wr + i * 16 + fr][fq];
            al[i] = *(const short8*)&Asl[wr + i * 16 + fr][fq];
        }
#pragma unroll
        for (int j = 0; j < 2; j++) {
            bh[j] = *(const short8*)&Bsh[wc + j * 16 + fr][fq];
            bl[j] = *(const short8*)&Bsl[wc + j * 16 + fr][fq];
        }
#pragma unroll
        for (int i = 0; i < 2; i++)
#pragma unroll
            for (int j = 0; j < 2; j++) {
                acc[i][j] = __builtin_amdgcn_mfma_f32_16x16x32_bf16(ah[i], bh[j], acc[i][j], 0, 0, 0);
                acc[i][j] = __builtin_amdgcn_mfma_f32_16x16x32_bf16(ah[i], bl[j], acc[i][j], 0, 0, 0);
                acc[i][j] = __builtin_amdgcn_mfma_f32_16x16x32_bf16(al[i], bh[j], acc[i][j], 0, 0, 0);
            }
        __syncthreads();
    }

    const int cr = (lane >> 4) * 4, cc = lane & 15;
#pragma unroll
    for (int i = 0; i < 2; i++)
#pragma unroll
        for (int j = 0; j < 2; j++) {
            const int gj = j0 + wc + j * 16 + cc;
            const float sq = rsq[gj];
#pragma unroll
            for (int r = 0; r < 4; r++) {
                const int gi = i0 + wr + i * 16 + cr + r;
                Out[(long)gi * 1024 + gj] = acc[i][j][r] * rsk[gi] * sq;
            }
        }
}

// ---------------------------------------------------------------------------
// Plain bf16 MFMA GEMM (T@V and final proj), 128x128, BK=32.
// ---------------------------------------------------------------------------
template <bool BIAS, bool OPERM, bool OUT_BF16>
__global__ __launch_bounds__(256) void gemm_bf16(
    const short* __restrict__ A, const short* __restrict__ B,
    const float* __restrict__ bias, void* __restrict__ OutV,
    int Kdim, int lda, int ldb, int ldo, long sA, long sB, long sO)
{
    __shared__ __align__(16) short As[128][40];
    __shared__ __align__(16) short Bs[128][40];

    const int tid  = threadIdx.x;
    const int lane = tid & 63, wv = tid >> 6;
    const int wr = (wv >> 1) * 64, wc = (wv & 1) * 64;
    const int i0 = blockIdx.x * 128, j0 = blockIdx.y * 128;

    floatx4 acc[4][4];
#pragma unroll
    for (int i = 0; i < 4; i++)
#pragma unroll
        for (int j = 0; j < 4; j++) acc[i][j] = {0.f, 0.f, 0.f, 0.f};

    const int sr = tid >> 2, sk = (tid & 3) * 8;
    const int fr = lane & 15, fq = (lane >> 4) * 8;
    const short* pa = A + (long)blockIdx.z * sA;
    const short* pb = B + (long)blockIdx.z * sB;

    for (int k0 = 0; k0 < Kdim; k0 += 32) {
#pragma unroll
        for (int p = 0; p < 2; p++) {
            *(short8*)&As[sr + p * 64][sk] =
                *(const short8*)(pa + (long)(i0 + sr + p * 64) * lda + k0 + sk);
            *(short8*)&Bs[sr + p * 64][sk] =
                *(const short8*)(pb + (long)(j0 + sr + p * 64) * ldb + k0 + sk);
        }
        __syncthreads();
        short8 af[4], bf[4];
#pragma unroll
        for (int i = 0; i < 4; i++) af[i] = *(const short8*)&As[wr + i * 16 + fr][fq];
#pragma unroll
        for (int j = 0; j < 4; j++) bf[j] = *(const short8*)&Bs[wc + j * 16 + fr][fq];
#pragma unroll
        for (int i = 0; i < 4; i++)
#pragma unroll
            for (int j = 0; j < 4; j++)
                acc[i][j] = __builtin_amdgcn_mfma_f32_16x16x32_bf16(af[i], bf[j], acc[i][j], 0, 0, 0);
        __syncthreads();
    }

    float* Of = nullptr; unsigned short* Ob = nullptr;
    if constexpr (OUT_BF16) Ob = (unsigned short*)OutV + (long)blockIdx.z * sO;
    else                    Of = (float*)OutV + (long)blockIdx.z * sO;
    const int cr = (lane >> 4) * 4, cc = lane & 15;
#pragma unroll
    for (int i = 0; i < 4; i++) {
#pragma unroll
        for (int j = 0; j < 4; j++) {
            const int gj = j0 + wc + j * 16 + cc;
            float bb = 0.0f;
            if constexpr (BIAS) bb = bias[gj];
#pragma unroll
            for (int r = 0; r < 4; r++) {
                const int gi = i0 + wr + i * 16 + cr + r;
                float v = acc[i][j][r] + bb;
                long idx;
                if constexpr (OPERM)
                    idx = (long)((gi & 63) * 128 + ((gi >> 6) & 15) * 8 + (gi >> 10)) * ldo + gj;
                else
                    idx = (long)gi * ldo + gj;
                if constexpr (OUT_BF16) Ob[idx] = f2bf(v);
                else                    Of[idx] = v;
            }
        }
    }
}

// ---------------------------------------------------------------------------
// Row reciprocal-norms from split pairs.
// ---------------------------------------------------------------------------
__global__ __launch_bounds__(256) void rownorm(
    const unsigned short* __restrict__ qh, const unsigned short* __restrict__ ql,
    const unsigned short* __restrict__ kh, const unsigned short* __restrict__ kl,
    float* __restrict__ rs)
{
    const int row  = blockIdx.x * 4 + (threadIdx.x >> 6);
    const int lane = threadIdx.x & 63;
    const unsigned short *ph, *pl;
    long r;
    if (row < 8192) { ph = qh; pl = ql; r = row; }
    else            { ph = kh; pl = kl; r = row - 8192; }
    const long o = r * 512 + lane * 8;
    ushort4 h0 = *(const ushort4*)(ph + o), h1 = *(const ushort4*)(ph + o + 4);
    ushort4 l0 = *(const ushort4*)(pl + o), l1 = *(const ushort4*)(pl + o + 4);
    float ss = 0.0f;
    const unsigned short hv[8] = {h0.x, h0.y, h0.z, h0.w, h1.x, h1.y, h1.z, h1.w};
    const unsigned short lv[8] = {l0.x, l0.y, l0.z, l0.w, l1.x, l1.y, l1.z, l1.w};
#pragma unroll
    for (int i = 0; i < 8; i++) {
        const float v = bf2f(hv[i]) + bf2f(lv[i]);
        ss = fmaf(v, v, ss);
    }
#pragma unroll
    for (int off = 32; off; off >>= 1) ss += __shfl_xor(ss, off, 64);
    if (lane == 0) rs[row] = 1.0f / fmaxf(sqrtf(ss), 1e-12f);
}

// ---------------------------------------------------------------------------
// Sinkhorn: 2 problems per wave (ILP-2 hides DS/DPP/rcp latency of the
// serial per-iteration chain), rotated dual layouts + DPP all-gathers,
// 3-parallel shfl_xor(16/32/48) = one DS round-trip per problem per iter.
// Math identical to rounds 3-6 (multiplicative form of the reference).
// ---------------------------------------------------------------------------
__global__ __launch_bounds__(256, 1) void sinkhorn6(
    const float* __restrict__ sim, float* __restrict__ score,
    unsigned short* __restrict__ Tt)
{
    const int lane = threadIdx.x & 63;
    const int w    = blockIdx.x * 4 + (threadIdx.x >> 6);   // wave id 0..1023
    const int bk0  = w * 2;                                  // problems bk0, bk0+1
    const int m = lane & 15, g = lane >> 4;

    // probe rho_j: pass (lane&15) through row_ror:j  (direction-proof)
    int idx[16];
    idx[0] = m;
    idx[1]  = RRI(m, 0x121); idx[2]  = RRI(m, 0x122); idx[3]  = RRI(m, 0x123);
    idx[4]  = RRI(m, 0x124); idx[5]  = RRI(m, 0x125); idx[6]  = RRI(m, 0x126);
    idx[7]  = RRI(m, 0x127); idx[8]  = RRI(m, 0x128); idx[9]  = RRI(m, 0x129);
    idx[10] = RRI(m, 0x12a); idx[11] = RRI(m, 0x12b); idx[12] = RRI(m, 0x12c);
    idx[13] = RRI(m, 0x12d); idx[14] = RRI(m, 0x12e); idx[15] = RRI(m, 0x12f);

    float K1[2][16], K2R[2][16], sv[2][16];
#pragma unroll
    for (int p = 0; p < 2; p++) {
        const float* S = sim + (long)(bk0 + p) * 1024;
#pragma unroll
        for (int j = 0; j < 16; j++) {
            K1[p][j] = __expf((S[m * 64 + g * 16 + idx[j]] - 1.0f) * 20.0f);
            const float s_ = S[idx[j] * 64 + lane];
            sv[p][j]  = s_;
            K2R[p][j] = __expf((s_ - 1.0f) * 20.0f);
        }
    }

    const float muP = 0.0625f + 1e-8f;      // exp(log(mu + 1e-8))
    const float nuP = 0.015625f + 1e-8f;
    float b[2] = {1.0f, 1.0f};
    float aB[2][16], bB[2][16];
#pragma unroll
    for (int p = 0; p < 2; p++)
#pragma unroll
        for (int j = 0; j < 16; j++) bB[p][j] = 1.0f;

#pragma unroll 1
    for (int it = 0; it < 100; it++) {
        // u-dots (both problems)
        float s[2];
#pragma unroll
        for (int p = 0; p < 2; p++) {
            float s0 = 0, s1 = 0, s2 = 0, s3 = 0;
#pragma unroll
            for (int j = 0; j < 4; j++) {
                s0 = fmaf(K1[p][j],      bB[p][j],      s0);
                s1 = fmaf(K1[p][4 + j],  bB[p][4 + j],  s1);
                s2 = fmaf(K1[p][8 + j],  bB[p][8 + j],  s2);
                s3 = fmaf(K1[p][12 + j], bB[p][12 + j], s3);
            }
            s[p] = (s0 + s1) + (s2 + s3);
        }
        // 6 bpermutes in flight, one drain: xor-tree sum = s + r16 + r32 + r48
        const float x16_0 = __shfl_xor(s[0], 16, 64);
        const float x32_0 = __shfl_xor(s[0], 32, 64);
        const float x48_0 = __shfl_xor(s[0], 48, 64);
        const float x16_1 = __shfl_xor(s[1], 16, 64);
        const float x32_1 = __shfl_xor(s[1], 32, 64);
        const float x48_1 = __shfl_xor(s[1], 48, 64);
        const float a0 = muP * fastrcp((s[0] + x16_0) + (x32_0 + x48_0));
        const float a1 = muP * fastrcp((s[1] + x16_1) + (x32_1 + x48_1));
        GATH16(aB[0], a0);
        GATH16(aB[1], a1);
        // v-dots (both problems)
#pragma unroll
        for (int p = 0; p < 2; p++) {
            float t0 = 0, t1 = 0, t2 = 0, t3 = 0;
#pragma unroll
            for (int j = 0; j < 4; j++) {
                t0 = fmaf(K2R[p][j],      aB[p][j],      t0);
                t1 = fmaf(K2R[p][4 + j],  aB[p][4 + j],  t1);
                t2 = fmaf(K2R[p][8 + j],  aB[p][8 + j],  t2);
                t3 = fmaf(K2R[p][12 + j], aB[p][12 + j], t3);
            }
            b[p] = nuP * fastrcp((t0 + t1) + (t2 + t3));
        }
        GATH16(bB[0], b[0]);
        GATH16(bB[1], b[1]);
    }

#pragma unroll
    for (int p = 0; p < 2; p++) {
        const int bk = bk0 + p;
        float* Sc = score + (long)bk * 1024;
        unsigned short* Tp = Tt + (long)(bk >> 8) * 262144 + (bk & 255);
#pragma unroll
        for (int j = 0; j < 16; j++) {
            const int row = idx[j];
            const float Tv = aB[p][j] * K2R[p][j] * b[p];
            Sc[row * 64 + lane] = 1024.0f * sv[p][j] * Tv;
            Tp[(long)(row * 64 + lane) * 256] = f2bf(Tv);
        }
    }
}

extern "C" void kernel_launch(void* const* d_in, const int* in_sizes, int n_in,
                              void* d_out, int out_size, void* d_ws, size_t ws_size,
                              hipStream_t stream)
{
    (void)in_sizes; (void)n_in; (void)out_size; (void)ws_size;
    const float* xq = (const float*)d_in[0];
    const float* xk = (const float*)d_in[1];
    const float* xv = (const float*)d_in[2];
    const float* Wq = (const float*)d_in[3];
    const float* Wk = (const float*)d_in[4];
    const float* Wv = (const float*)d_in[5];
    const float* Wp = (const float*)d_in[6];
    const float* bp = (const float*)d_in[7];

    float* out_x     = (float*)d_out;           // (Nq,M,B,C) = 8192 x 512
    float* out_score = out_x + 8192L * 512;     // (B,K,M,Nq) = 2048 x 1024

    // workspace (47.1 MB of the proven 48 MB); regions reused across phases
    char* W = (char*)d_ws;
    const long MB = 1 << 20;
    unsigned short* qh   = (unsigned short*)(W + 0);        // 8MB [b][mn][c]
    unsigned short* ql   = (unsigned short*)(W + 8 * MB);   // 8MB
    unsigned short* xq_h = (unsigned short*)(W + 16 * MB);  // 8MB, dead after qkv
    float*          simb = (float*)(W + 16 * MB);           // 8MB (reuse)
    unsigned short* xq_l = (unsigned short*)(W + 24 * MB);  // 8MB, dead after qkv
    unsigned short* xpre = (unsigned short*)(W + 24 * MB);  // 8MB (reuse)
    unsigned short* xk_h = (unsigned short*)(W + 32 * MB);  // 2MB, dead after qkv
    unsigned short* xk_l = (unsigned short*)(W + 34 * MB);  // 2MB
    unsigned short* Tt   = (unsigned short*)(W + 32 * MB);  // 4MB (reuse)
    unsigned short* xv_b = (unsigned short*)(W + 36 * MB);  // 2MB
    unsigned short* kh   = (unsigned short*)(W + 38 * MB);  // 2MB [b][k'][c]
    unsigned short* kl   = (unsigned short*)(W + 40 * MB);  // 2MB
    unsigned short* vt   = (unsigned short*)(W + 42 * MB);  // 2MB [b][c][k']
    unsigned short* wqh  = (unsigned short*)(W + 44 * MB);
    unsigned short* wql  = (unsigned short*)(W + 44 * MB + 1 * 524288);
    unsigned short* wkh  = (unsigned short*)(W + 44 * MB + 2 * 524288);
    unsigned short* wkl  = (unsigned short*)(W + 44 * MB + 3 * 524288);
    unsigned short* wvb  = (unsigned short*)(W + 44 * MB + 4 * 524288);
    unsigned short* wpb  = (unsigned short*)(W + 44 * MB + 5 * 524288);
    float*          rs   = (float*)(W + 47 * MB);           // 40KB

    const dim3 blk(256);

    // 1: precast/split all fp32 operands
    prep<<<7168, blk, 0, stream>>>(xq, xk, xv, Wq, Wk, Wv, Wp,
                                   xq_h, xq_l, xk_h, xk_l, xv_b,
                                   wqh, wql, wkh, wkl, wvb, wpb);

    // 2: fused q/k/v projections on bf16 operands
    gemm_qkv2<<<dim3(96, 4), blk, 0, stream>>>(
        xq_h, xq_l, xk_h, xk_l, xv_b, wqh, wql, wkh, wkl, wvb,
        qh, ql, kh, kl, vt);

    // 3: reciprocal row norms
    rownorm<<<2560, blk, 0, stream>>>(qh, ql, kh, kl, rs);

    // 4: sim[b][k'][mn] = (k.q) * rs_k * rs_q
    gemm_sim64<<<dim3(4, 16, 8), blk, 0, stream>>>(
        (const short*)kh, (const short*)kl, (const short*)qh, (const short*)ql,
        simb, rs);

    // 5: Sinkhorn (2 problems/wave) -> score (out) + T bf16 [b][mn][k']
    sinkhorn6<<<256, blk, 0, stream>>>(simb, out_score, Tt);

    // 6: xpre[b][mn][c] = sum_k' T[b][mn][k'] * v[b][k'][c]
    gemm_bf16<false, false, true><<<dim3(8, 4, 8), blk, 0, stream>>>(
        (const short*)Tt, (const short*)vt, nullptr, xpre,
        256, 256, 256, 512, 262144, 131072, 524288);

    // 7: x = xpre @ Wp^T + bp, rows (b,mn)->(n,m,b), fp32 out
    gemm_bf16<true, true, false><<<dim3(64, 4), blk, 0, stream>>>(
        (const short*)xpre, (const short*)wpb, bp, out_x,
        512, 512, 512, 512, 0, 0, 0);
}